// Round 18
// baseline (1037.682 us; speedup 1.0000x reference)
//
#include <hip/hip_runtime.h>

typedef __attribute__((ext_vector_type(8))) short bf16x8;
typedef __attribute__((ext_vector_type(4))) float f32x4;
typedef __attribute__((ext_vector_type(4))) unsigned short us4;
typedef __attribute__((ext_vector_type(8))) unsigned short us8;

#define NROWS 262144
#define KC 256
#define DD 256
#define TAU 1.5e-3f
#define FCAP 65536

// ===== bit-exact numpy emulation helpers =====
__device__ __forceinline__ float np_pw128_sq(const float* a) {
    float r[8];
#pragma unroll
    for (int j = 0; j < 8; ++j) r[j] = __fmul_rn(a[j], a[j]);
    for (int i = 8; i < 128; i += 8) {
#pragma unroll
        for (int j = 0; j < 8; ++j)
            r[j] = __fadd_rn(r[j], __fmul_rn(a[i + j], a[i + j]));
    }
    float t01 = __fadd_rn(r[0], r[1]), t23 = __fadd_rn(r[2], r[3]);
    float t45 = __fadd_rn(r[4], r[5]), t67 = __fadd_rn(r[6], r[7]);
    return __fadd_rn(__fadd_rn(t01, t23), __fadd_rn(t45, t67));
}
__device__ __forceinline__ float np_sum256_sq(const float* a) {
    return __fadd_rn(np_pw128_sq(a), np_pw128_sq(a + 128));
}
__device__ __forceinline__ unsigned short bf16_rne(float x) {
    unsigned b = __float_as_uint(x);
    b += 0x7FFFu + ((b >> 16) & 1u);
    return (unsigned short)(b >> 16);
}

// ---------- prep ----------
__global__ void vq_prep(const float* __restrict__ emb, float* __restrict__ se,
                        double* __restrict__ accum, int* __restrict__ gcnt) {
    int k = threadIdx.x;
    if (k == 0) { *accum = 0.0; *gcnt = 0; }
    se[k] = np_sum256_sq(emb + (size_t)k * DD);
}

// ---------- split emb -> frag-linear bf16 plane (r16 layout) ----------
__global__ void vq_split(const float* __restrict__ emb, unsigned short* __restrict__ ph) {
    int f = (blockIdx.x * 256 + threadIdx.x) * 4;
    float4 v = *reinterpret_cast<const float4*>(emb + f);
    int k = f >> 8, d = f & 255;
    int off = (d >> 5) * 8192 + (k >> 4) * 512 + (k & 15) * 32 + ((d >> 3) & 3) * 8 + (d & 7);
    us4 h;
    h[0] = bf16_rne(v.x); h[1] = bf16_rne(v.y);
    h[2] = bf16_rne(v.z); h[3] = bf16_rne(v.w);
    *reinterpret_cast<us4*>(ph + off) = h;
}

// ---------- main: 16 independent waves, e-plane resident in 128KB dynamic LDS ----------
__global__ __launch_bounds__(1024)
void vq_main(const float* __restrict__ ze, const float* __restrict__ emb,
             const unsigned short* __restrict__ ph, const float* __restrict__ se_g,
             float* __restrict__ out_zq, float* __restrict__ out_inds,
             double* __restrict__ accum, int* __restrict__ glist, int* __restrict__ gcnt)
{
    extern __shared__ __attribute__((aligned(16))) unsigned short ldsE[];  // 128 KB e-plane
    __shared__ float se_s[KC];
    __shared__ float lred[16];

    const int t = threadIdx.x;       // 0..1023
    const int wv = t >> 6;           // wave 0..15
    const int lane = t & 63;
    const int q = (lane >> 4) & 3;
    const int c = lane & 15;

    // stage e-plane once (coalesced 16B copies), + se
    if (t < KC) se_s[t] = se_g[t];
#pragma unroll
    for (int i = 0; i < 8; ++i) {
        int idx = i * 1024 + t;
        *reinterpret_cast<us8*>(&ldsE[idx * 8]) = *reinterpret_cast<const us8*>(ph + idx * 8);
    }
    __syncthreads();   // ONLY block-wide sync before epilogue

    float sz_acc = 0.f, lossv = 0.f;

    for (int s = 0; s < 4; ++s) {
        const int g = blockIdx.x * 64 + wv * 4 + s;     // 16-row group
        const size_t r0 = (size_t)g * 16;

        // ---- z: load (scattered) + cvt -> 8 frags; sz on the fly; dci pairs to cap regs ----
        bf16x8 zfrag[8];
        const float* zb = ze + (r0 + c) * DD + q * 8;
#pragma unroll
        for (int dp = 0; dp < 4; ++dp) {
            float4 a0 = *reinterpret_cast<const float4*>(zb + (2 * dp) * 32);
            float4 b0 = *reinterpret_cast<const float4*>(zb + (2 * dp) * 32 + 4);
            float4 a1 = *reinterpret_cast<const float4*>(zb + (2 * dp + 1) * 32);
            float4 b1 = *reinterpret_cast<const float4*>(zb + (2 * dp + 1) * 32 + 4);
            sz_acc = fmaf(a0.x, a0.x, sz_acc); sz_acc = fmaf(a0.y, a0.y, sz_acc);
            sz_acc = fmaf(a0.z, a0.z, sz_acc); sz_acc = fmaf(a0.w, a0.w, sz_acc);
            sz_acc = fmaf(b0.x, b0.x, sz_acc); sz_acc = fmaf(b0.y, b0.y, sz_acc);
            sz_acc = fmaf(b0.z, b0.z, sz_acc); sz_acc = fmaf(b0.w, b0.w, sz_acc);
            sz_acc = fmaf(a1.x, a1.x, sz_acc); sz_acc = fmaf(a1.y, a1.y, sz_acc);
            sz_acc = fmaf(a1.z, a1.z, sz_acc); sz_acc = fmaf(a1.w, a1.w, sz_acc);
            sz_acc = fmaf(b1.x, b1.x, sz_acc); sz_acc = fmaf(b1.y, b1.y, sz_acc);
            sz_acc = fmaf(b1.z, b1.z, sz_acc); sz_acc = fmaf(b1.w, b1.w, sz_acc);
            us8 h0, h1;
            h0[0] = bf16_rne(a0.x); h0[1] = bf16_rne(a0.y); h0[2] = bf16_rne(a0.z); h0[3] = bf16_rne(a0.w);
            h0[4] = bf16_rne(b0.x); h0[5] = bf16_rne(b0.y); h0[6] = bf16_rne(b0.z); h0[7] = bf16_rne(b0.w);
            h1[0] = bf16_rne(a1.x); h1[1] = bf16_rne(a1.y); h1[2] = bf16_rne(a1.z); h1[3] = bf16_rne(a1.w);
            h1[4] = bf16_rne(b1.x); h1[5] = bf16_rne(b1.y); h1[6] = bf16_rne(b1.z); h1[7] = bf16_rne(b1.w);
            zfrag[2 * dp]     = __builtin_bit_cast(bf16x8, h0);
            zfrag[2 * dp + 1] = __builtin_bit_cast(bf16x8, h1);
        }

        // ---- 2 code-passes x (8 dci x 8 nf) MFMA from LDS; argmin state carried ----
        float v1[4], v2[4]; int k1[4];
#pragma unroll
        for (int j = 0; j < 4; ++j) { v1[j] = 3.4e38f; v2[j] = 3.4e38f; k1[j] = 0x7fffffff; }
#pragma unroll
        for (int p = 0; p < 2; ++p) {
            f32x4 acc[8];
#pragma unroll
            for (int n = 0; n < 8; ++n) acc[n] = (f32x4){0.f, 0.f, 0.f, 0.f};
#pragma unroll
            for (int dci = 0; dci < 8; ++dci) {
#pragma unroll
                for (int n = 0; n < 8; ++n) {
                    bf16x8 bf = *reinterpret_cast<const bf16x8*>(
                        &ldsE[dci * 8192 + (p * 8 + n) * 512 + c * 32 + q * 8]);
                    acc[n] = __builtin_amdgcn_mfma_f32_16x16x32_bf16(zfrag[dci], bf, acc[n], 0, 0, 0);
                }
            }
#pragma unroll
            for (int n = 0; n < 8; ++n) {
                int k = (p * 8 + n) * 16 + c;
                float sev = se_s[k];
#pragma unroll
                for (int j = 0; j < 4; ++j) {
                    float dv = fmaf(-2.f, acc[n][j], sev);
                    if (dv < v1[j]) { v2[j] = v1[j]; v1[j] = dv; k1[j] = k; }
                    else if (dv < v2[j]) { v2[j] = dv; }
                }
            }
        }

        // ---- merge across the 16 c-lanes (xor 1,2,4,8) per row j ----
#pragma unroll
        for (int j = 0; j < 4; ++j) {
#pragma unroll
            for (int off = 1; off < 16; off <<= 1) {
                float ov1 = __shfl_xor(v1[j], off, 64);
                float ov2 = __shfl_xor(v2[j], off, 64);
                int   ok1 = __shfl_xor(k1[j], off, 64);
                bool other = (ov1 < v1[j]) || (ov1 == v1[j] && ok1 < k1[j]);
                float nv2 = other ? fminf(v1[j], ov2) : fminf(v2[j], ov1);
                if (other) { v1[j] = ov1; k1[j] = ok1; }
                v2[j] = nv2;
            }
            if (c == 0) {
                size_t row = r0 + 4 * q + j;
                out_inds[row] = (float)k1[j];
                lossv += v1[j];
                if (v2[j] - v1[j] < TAU) {
                    int s_ = atomicAdd(gcnt, 1);
                    if (s_ < FCAP) glist[s_] = (int)row;
                }
            }
        }

        // ---- fused z_q write: k1[j] uniform across c-group; dense 256B segments ----
#pragma unroll
        for (int j = 0; j < 4; ++j) {
            size_t row = r0 + 4 * q + j;
            const float* ep = emb + (size_t)k1[j] * DD;
            float* op = out_zq + row * DD;
#pragma unroll
            for (int i = 0; i < 4; ++i) {
                float4 v = *reinterpret_cast<const float4*>(ep + (i * 16 + c) * 4);
                *reinterpret_cast<float4*>(op + (i * 16 + c) * 4) = v;
            }
        }
    }

    // ---- loss partial: wave-reduce then block-reduce ----
    float part = sz_acc + lossv;
#pragma unroll
    for (int off = 1; off < 64; off <<= 1) part += __shfl_xor(part, off, 64);
    if (lane == 0) lred[wv] = part;
    __syncthreads();
    if (t == 0) {
        float s = 0.f;
        for (int i = 0; i < 16; ++i) s += lred[i];
        atomicAdd(accum, (double)s);
    }
}

// ---------- deferred fix: bit-exact np fp32 pipeline, batched 16 rows (rewrites inds + z_q) ----------
__global__ __launch_bounds__(256)
void vq_fix(const float* __restrict__ ze, const float* __restrict__ emb,
            const float* __restrict__ se_g, const int* __restrict__ glist,
            const int* __restrict__ gcnt, float* __restrict__ out_zq,
            float* __restrict__ out_inds)
{
    __shared__ float dq[16][256];
    __shared__ float srow_s[16];
    __shared__ int   rowid_s[16];
    __shared__ int   klds[16];

    const int t = threadIdx.x;
    int F = *gcnt; if (F > FCAP) F = FCAP;
    const float se_k = se_g[t];
    const float4* e4p = reinterpret_cast<const float4*>(emb + (size_t)t * DD);

    for (int g = blockIdx.x * 16; g < F; g += gridDim.x * 16) {
        __syncthreads();
        if (t < 16) {
            int idx = g + t; if (idx > F - 1) idx = F - 1;
            int row = glist[idx];
            rowid_s[t] = row;
            srow_s[t] = np_sum256_sq(ze + (size_t)row * DD);
        }
        __syncthreads();

        const float* zp[16];
#pragma unroll
        for (int r = 0; r < 16; ++r)
            zp[r] = ze + (size_t)__builtin_amdgcn_readfirstlane(rowid_s[r]) * DD;

        float m32[16];
#pragma unroll
        for (int r = 0; r < 16; ++r) m32[r] = 0.f;
        for (int d4 = 0; d4 < 64; ++d4) {
            float4 e4 = e4p[d4];
            const int d = d4 * 4;
#pragma unroll
            for (int r = 0; r < 16; ++r) {
                m32[r] = __fmaf_rn(zp[r][d + 0], e4.x, m32[r]);
                m32[r] = __fmaf_rn(zp[r][d + 1], e4.y, m32[r]);
                m32[r] = __fmaf_rn(zp[r][d + 2], e4.z, m32[r]);
                m32[r] = __fmaf_rn(zp[r][d + 3], e4.w, m32[r]);
            }
        }
#pragma unroll
        for (int r = 0; r < 16; ++r) {
            float A = __fadd_rn(srow_s[r], se_k);
            dq[r][t] = __fsub_rn(A, __fmul_rn(2.0f, m32[r]));
        }
        __syncthreads();

        {
            const int r = t >> 4, p = t & 15;
            float bv = 3.4e38f; int bk = 0x7fffffff;
#pragma unroll
            for (int i = 0; i < 16; ++i) {
                int k = p * 16 + i;
                float v = dq[r][k];
                if (v < bv) { bv = v; bk = k; }
            }
#pragma unroll
            for (int off = 1; off < 16; off <<= 1) {
                float ov = __shfl_xor(bv, off, 64);
                int   ok = __shfl_xor(bk, off, 64);
                if (ov < bv || (ov == bv && ok < bk)) { bv = ov; bk = ok; }
            }
            if (p == 0) klds[r] = bk;
        }
        __syncthreads();

        int R = F - g; if (R > 16) R = 16;
#pragma unroll
        for (int r = 0; r < 16; ++r) {
            if (r < R) {
                int row = rowid_s[r];
                int kk  = klds[r];
                out_zq[(size_t)row * DD + t] = emb[(size_t)kk * DD + t];
                if (t == 0) out_inds[row] = (float)kk;
            }
        }
    }
}

// ---------- finalize ----------
__global__ void vq_fin(const double* __restrict__ accum, float* __restrict__ out_loss) {
    *out_loss = (float)(1.25 * (*accum) / ((double)NROWS * (double)DD));
}

extern "C" void kernel_launch(void* const* d_in, const int* in_sizes, int n_in,
                              void* d_out, int out_size, void* d_ws, size_t ws_size,
                              hipStream_t stream) {
    const float* ze  = (const float*)d_in[0];
    const float* emb = (const float*)d_in[1];
    float* out      = (float*)d_out;
    float* out_zq   = out;
    float* out_inds = out + (size_t)NROWS * DD;
    float* out_loss = out + (size_t)NROWS * DD + NROWS;

    double* accum = (double*)d_ws;                                        // @0
    int*    gcnt  = (int*)((char*)d_ws + 8);                              // @8
    float*  se    = (float*)((char*)d_ws + 256);                          // @256
    int*    glist = (int*)((char*)d_ws + 4096);                           // @4K, 256KB
    unsigned short* ph = (unsigned short*)((char*)d_ws + 4096 + 262144);  // 128KB

    // allow 128KB dynamic LDS for vq_main (host-side attribute; not a stream op)
    (void)hipFuncSetAttribute((const void*)vq_main,
                              hipFuncAttributeMaxDynamicSharedMemorySize, 131072);

    vq_prep<<<1, 256, 0, stream>>>(emb, se, accum, gcnt);
    vq_split<<<KC * DD / (256 * 4), 256, 0, stream>>>(emb, ph);
    vq_main<<<NROWS / 1024, 1024, 131072, stream>>>(ze, emb, ph, se, out_zq, out_inds,
                                                    accum, glist, gcnt);
    vq_fix<<<1024, 256, 0, stream>>>(ze, emb, se, glist, gcnt, out_zq, out_inds);
    vq_fin<<<1, 1, 0, stream>>>(accum, out_loss);
}

// Round 19
// 1017.223 us; speedup vs baseline: 1.0201x; 1.0201x over previous
//
#include <hip/hip_runtime.h>

typedef __attribute__((ext_vector_type(8))) short bf16x8;
typedef __attribute__((ext_vector_type(4))) float f32x4;
typedef __attribute__((ext_vector_type(4))) unsigned short us4;
typedef __attribute__((ext_vector_type(8))) unsigned short us8;

#define NROWS 262144
#define KC 256
#define DD 256
#define TAU 1.5e-3f
#define FCAP 65536

// ===== bit-exact numpy emulation helpers =====
__device__ __forceinline__ float np_pw128_sq(const float* a) {
    float r[8];
#pragma unroll
    for (int j = 0; j < 8; ++j) r[j] = __fmul_rn(a[j], a[j]);
    for (int i = 8; i < 128; i += 8) {
#pragma unroll
        for (int j = 0; j < 8; ++j)
            r[j] = __fadd_rn(r[j], __fmul_rn(a[i + j], a[i + j]));
    }
    float t01 = __fadd_rn(r[0], r[1]), t23 = __fadd_rn(r[2], r[3]);
    float t45 = __fadd_rn(r[4], r[5]), t67 = __fadd_rn(r[6], r[7]);
    return __fadd_rn(__fadd_rn(t01, t23), __fadd_rn(t45, t67));
}
__device__ __forceinline__ float np_sum256_sq(const float* a) {
    return __fadd_rn(np_pw128_sq(a), np_pw128_sq(a + 128));
}
__device__ __forceinline__ unsigned short bf16_rne(float x) {
    unsigned b = __float_as_uint(x);
    b += 0x7FFFu + ((b >> 16) & 1u);
    return (unsigned short)(b >> 16);
}

// ---------- prep ----------
__global__ void vq_prep(const float* __restrict__ emb, float* __restrict__ se,
                        double* __restrict__ accum, int* __restrict__ gcnt) {
    int k = threadIdx.x;
    if (k == 0) { *accum = 0.0; *gcnt = 0; }
    se[k] = np_sum256_sq(emb + (size_t)k * DD);
}

// ---------- split emb -> frag-linear bf16 plane (r16 layout) ----------
__global__ void vq_split(const float* __restrict__ emb, unsigned short* __restrict__ ph) {
    int f = (blockIdx.x * 256 + threadIdx.x) * 4;
    float4 v = *reinterpret_cast<const float4*>(emb + f);
    int k = f >> 8, d = f & 255;
    int off = (d >> 5) * 8192 + (k >> 4) * 512 + (k & 15) * 32 + ((d >> 3) & 3) * 8 + (d & 7);
    us4 h;
    h[0] = bf16_rne(v.x); h[1] = bf16_rne(v.y);
    h[2] = bf16_rne(v.z); h[3] = bf16_rne(v.w);
    *reinterpret_cast<us4*>(ph + off) = h;
}

// ---------- main: 16 independent waves, e-plane in 128KB dynamic LDS, NO spill ----------
__global__ __launch_bounds__(1024, 4)
void vq_main(const float* __restrict__ ze, const float* __restrict__ emb,
             const unsigned short* __restrict__ ph, const float* __restrict__ se_g,
             float* __restrict__ out_zq, float* __restrict__ out_inds,
             double* __restrict__ accum, int* __restrict__ glist, int* __restrict__ gcnt)
{
    extern __shared__ __attribute__((aligned(16))) unsigned short ldsE[];  // 128 KB e-plane
    __shared__ float se_s[KC];
    __shared__ float lred[16];

    const int t = threadIdx.x;       // 0..1023
    const int wv = t >> 6;           // wave 0..15
    const int lane = t & 63;
    const int q = (lane >> 4) & 3;
    const int c = lane & 15;

    // stage e-plane once (coalesced 16B copies), + se
    if (t < KC) se_s[t] = se_g[t];
#pragma unroll
    for (int i = 0; i < 8; ++i) {
        int idx = i * 1024 + t;
        *reinterpret_cast<us8*>(&ldsE[idx * 8]) = *reinterpret_cast<const us8*>(ph + idx * 8);
    }
    __syncthreads();   // ONLY block-wide sync before epilogue

    float sz_acc = 0.f, lossv = 0.f;

    for (int s = 0; s < 4; ++s) {
        const int g = blockIdx.x * 64 + wv * 4 + s;     // 16-row group
        const size_t r0 = (size_t)g * 16;

        // ---- z: load (scattered) + cvt -> 8 frags; sz on the fly; pairs cap transients ----
        bf16x8 zfrag[8];
        const float* zb = ze + (r0 + c) * DD + q * 8;
#pragma unroll
        for (int dp = 0; dp < 4; ++dp) {
            float4 a0 = *reinterpret_cast<const float4*>(zb + (2 * dp) * 32);
            float4 b0 = *reinterpret_cast<const float4*>(zb + (2 * dp) * 32 + 4);
            float4 a1 = *reinterpret_cast<const float4*>(zb + (2 * dp + 1) * 32);
            float4 b1 = *reinterpret_cast<const float4*>(zb + (2 * dp + 1) * 32 + 4);
            sz_acc = fmaf(a0.x, a0.x, sz_acc); sz_acc = fmaf(a0.y, a0.y, sz_acc);
            sz_acc = fmaf(a0.z, a0.z, sz_acc); sz_acc = fmaf(a0.w, a0.w, sz_acc);
            sz_acc = fmaf(b0.x, b0.x, sz_acc); sz_acc = fmaf(b0.y, b0.y, sz_acc);
            sz_acc = fmaf(b0.z, b0.z, sz_acc); sz_acc = fmaf(b0.w, b0.w, sz_acc);
            sz_acc = fmaf(a1.x, a1.x, sz_acc); sz_acc = fmaf(a1.y, a1.y, sz_acc);
            sz_acc = fmaf(a1.z, a1.z, sz_acc); sz_acc = fmaf(a1.w, a1.w, sz_acc);
            sz_acc = fmaf(b1.x, b1.x, sz_acc); sz_acc = fmaf(b1.y, b1.y, sz_acc);
            sz_acc = fmaf(b1.z, b1.z, sz_acc); sz_acc = fmaf(b1.w, b1.w, sz_acc);
            us8 h0, h1;
            h0[0] = bf16_rne(a0.x); h0[1] = bf16_rne(a0.y); h0[2] = bf16_rne(a0.z); h0[3] = bf16_rne(a0.w);
            h0[4] = bf16_rne(b0.x); h0[5] = bf16_rne(b0.y); h0[6] = bf16_rne(b0.z); h0[7] = bf16_rne(b0.w);
            h1[0] = bf16_rne(a1.x); h1[1] = bf16_rne(a1.y); h1[2] = bf16_rne(a1.z); h1[3] = bf16_rne(a1.w);
            h1[4] = bf16_rne(b1.x); h1[5] = bf16_rne(b1.y); h1[6] = bf16_rne(b1.z); h1[7] = bf16_rne(b1.w);
            zfrag[2 * dp]     = __builtin_bit_cast(bf16x8, h0);
            zfrag[2 * dp + 1] = __builtin_bit_cast(bf16x8, h1);
        }

        // ---- 4 code-passes x (8 dci x 4 nf) MFMA from LDS (acc[4] = 16 regs, no spill) ----
        float v1[4], v2[4]; int k1[4];
#pragma unroll
        for (int j = 0; j < 4; ++j) { v1[j] = 3.4e38f; v2[j] = 3.4e38f; k1[j] = 0x7fffffff; }
#pragma unroll
        for (int p = 0; p < 4; ++p) {
            f32x4 acc[4];
#pragma unroll
            for (int n = 0; n < 4; ++n) acc[n] = (f32x4){0.f, 0.f, 0.f, 0.f};
#pragma unroll
            for (int dci = 0; dci < 8; ++dci) {
#pragma unroll
                for (int n = 0; n < 4; ++n) {
                    bf16x8 bf = *reinterpret_cast<const bf16x8*>(
                        &ldsE[dci * 8192 + (p * 4 + n) * 512 + c * 32 + q * 8]);
                    acc[n] = __builtin_amdgcn_mfma_f32_16x16x32_bf16(zfrag[dci], bf, acc[n], 0, 0, 0);
                }
            }
#pragma unroll
            for (int n = 0; n < 4; ++n) {
                int k = (p * 4 + n) * 16 + c;
                float sev = se_s[k];
#pragma unroll
                for (int j = 0; j < 4; ++j) {
                    float dv = fmaf(-2.f, acc[n][j], sev);
                    if (dv < v1[j]) { v2[j] = v1[j]; v1[j] = dv; k1[j] = k; }
                    else if (dv < v2[j]) { v2[j] = dv; }
                }
            }
        }

        // ---- merge across the 16 c-lanes (xor 1,2,4,8) per row j ----
#pragma unroll
        for (int j = 0; j < 4; ++j) {
#pragma unroll
            for (int off = 1; off < 16; off <<= 1) {
                float ov1 = __shfl_xor(v1[j], off, 64);
                float ov2 = __shfl_xor(v2[j], off, 64);
                int   ok1 = __shfl_xor(k1[j], off, 64);
                bool other = (ov1 < v1[j]) || (ov1 == v1[j] && ok1 < k1[j]);
                float nv2 = other ? fminf(v1[j], ov2) : fminf(v2[j], ov1);
                if (other) { v1[j] = ov1; k1[j] = ok1; }
                v2[j] = nv2;
            }
            if (c == 0) {
                size_t row = r0 + 4 * q + j;
                out_inds[row] = (float)k1[j];
                lossv += v1[j];
                if (v2[j] - v1[j] < TAU) {
                    int s_ = atomicAdd(gcnt, 1);
                    if (s_ < FCAP) glist[s_] = (int)row;
                }
            }
        }

        // ---- fused z_q write: k1[j] uniform across c-group; 256B segments ----
#pragma unroll
        for (int j = 0; j < 4; ++j) {
            size_t row = r0 + 4 * q + j;
            const float* ep = emb + (size_t)k1[j] * DD;
            float* op = out_zq + row * DD;
#pragma unroll
            for (int i = 0; i < 4; ++i) {
                float4 v = *reinterpret_cast<const float4*>(ep + (i * 16 + c) * 4);
                *reinterpret_cast<float4*>(op + (i * 16 + c) * 4) = v;
            }
        }
    }

    // ---- loss partial: wave-reduce then block-reduce ----
    float part = sz_acc + lossv;
#pragma unroll
    for (int off = 1; off < 64; off <<= 1) part += __shfl_xor(part, off, 64);
    if (lane == 0) lred[wv] = part;
    __syncthreads();
    if (t == 0) {
        float s = 0.f;
        for (int i = 0; i < 16; ++i) s += lred[i];
        atomicAdd(accum, (double)s);
    }
}

// ---------- deferred fix: bit-exact np fp32 pipeline, batched 16 rows (rewrites inds + z_q) ----------
__global__ __launch_bounds__(256)
void vq_fix(const float* __restrict__ ze, const float* __restrict__ emb,
            const float* __restrict__ se_g, const int* __restrict__ glist,
            const int* __restrict__ gcnt, float* __restrict__ out_zq,
            float* __restrict__ out_inds)
{
    __shared__ float dq[16][256];
    __shared__ float srow_s[16];
    __shared__ int   rowid_s[16];
    __shared__ int   klds[16];

    const int t = threadIdx.x;
    int F = *gcnt; if (F > FCAP) F = FCAP;
    const float se_k = se_g[t];
    const float4* e4p = reinterpret_cast<const float4*>(emb + (size_t)t * DD);

    for (int g = blockIdx.x * 16; g < F; g += gridDim.x * 16) {
        __syncthreads();
        if (t < 16) {
            int idx = g + t; if (idx > F - 1) idx = F - 1;
            int row = glist[idx];
            rowid_s[t] = row;
            srow_s[t] = np_sum256_sq(ze + (size_t)row * DD);
        }
        __syncthreads();

        const float* zp[16];
#pragma unroll
        for (int r = 0; r < 16; ++r)
            zp[r] = ze + (size_t)__builtin_amdgcn_readfirstlane(rowid_s[r]) * DD;

        float m32[16];
#pragma unroll
        for (int r = 0; r < 16; ++r) m32[r] = 0.f;
        for (int d4 = 0; d4 < 64; ++d4) {
            float4 e4 = e4p[d4];
            const int d = d4 * 4;
#pragma unroll
            for (int r = 0; r < 16; ++r) {
                m32[r] = __fmaf_rn(zp[r][d + 0], e4.x, m32[r]);
                m32[r] = __fmaf_rn(zp[r][d + 1], e4.y, m32[r]);
                m32[r] = __fmaf_rn(zp[r][d + 2], e4.z, m32[r]);
                m32[r] = __fmaf_rn(zp[r][d + 3], e4.w, m32[r]);
            }
        }
#pragma unroll
        for (int r = 0; r < 16; ++r) {
            float A = __fadd_rn(srow_s[r], se_k);
            dq[r][t] = __fsub_rn(A, __fmul_rn(2.0f, m32[r]));
        }
        __syncthreads();

        {
            const int r = t >> 4, p = t & 15;
            float bv = 3.4e38f; int bk = 0x7fffffff;
#pragma unroll
            for (int i = 0; i < 16; ++i) {
                int k = p * 16 + i;
                float v = dq[r][k];
                if (v < bv) { bv = v; bk = k; }
            }
#pragma unroll
            for (int off = 1; off < 16; off <<= 1) {
                float ov = __shfl_xor(bv, off, 64);
                int   ok = __shfl_xor(bk, off, 64);
                if (ov < bv || (ov == bv && ok < bk)) { bv = ov; bk = ok; }
            }
            if (p == 0) klds[r] = bk;
        }
        __syncthreads();

        int R = F - g; if (R > 16) R = 16;
#pragma unroll
        for (int r = 0; r < 16; ++r) {
            if (r < R) {
                int row = rowid_s[r];
                int kk  = klds[r];
                out_zq[(size_t)row * DD + t] = emb[(size_t)kk * DD + t];
                if (t == 0) out_inds[row] = (float)kk;
            }
        }
    }
}

// ---------- finalize ----------
__global__ void vq_fin(const double* __restrict__ accum, float* __restrict__ out_loss) {
    *out_loss = (float)(1.25 * (*accum) / ((double)NROWS * (double)DD));
}

extern "C" void kernel_launch(void* const* d_in, const int* in_sizes, int n_in,
                              void* d_out, int out_size, void* d_ws, size_t ws_size,
                              hipStream_t stream) {
    const float* ze  = (const float*)d_in[0];
    const float* emb = (const float*)d_in[1];
    float* out      = (float*)d_out;
    float* out_zq   = out;
    float* out_inds = out + (size_t)NROWS * DD;
    float* out_loss = out + (size_t)NROWS * DD + NROWS;

    double* accum = (double*)d_ws;                                        // @0
    int*    gcnt  = (int*)((char*)d_ws + 8);                              // @8
    float*  se    = (float*)((char*)d_ws + 256);                          // @256
    int*    glist = (int*)((char*)d_ws + 4096);                           // @4K, 256KB
    unsigned short* ph = (unsigned short*)((char*)d_ws + 4096 + 262144);  // 128KB

    (void)hipFuncSetAttribute((const void*)vq_main,
                              hipFuncAttributeMaxDynamicSharedMemorySize, 131072);

    vq_prep<<<1, 256, 0, stream>>>(emb, se, accum, gcnt);
    vq_split<<<KC * DD / (256 * 4), 256, 0, stream>>>(emb, ph);
    vq_main<<<NROWS / 1024, 1024, 131072, stream>>>(ze, emb, ph, se, out_zq, out_inds,
                                                    accum, glist, gcnt);
    vq_fix<<<1024, 256, 0, stream>>>(ze, emb, se, glist, gcnt, out_zq, out_inds);
    vq_fin<<<1, 1, 0, stream>>>(accum, out_loss);
}